// Round 13
// baseline (9630.821 us; speedup 1.0000x reference)
//
#include <hip/hip_runtime.h>

#define Nn 50000
#define Ee 800000
#define KIN 133      // 2*64 + 4 + 1
#define ES 68        // padded LDS tile stride (floats)
#define EPS 1e-5f

typedef unsigned short u16;
typedef __attribute__((ext_vector_type(8))) short bf16x8;
typedef __attribute__((ext_vector_type(4))) float f32x4;

// bf16 round-to-nearest-even pack/unpack
__device__ __forceinline__ u16 f2bf(float f) {
    union { float f; unsigned u; } v; v.f = f;
    unsigned r = (v.u + 0x7FFFu + ((v.u >> 16) & 1u)) >> 16;
    return (u16)r;
}
__device__ __forceinline__ float bf2f(u16 s) {
    union { unsigned u; float f; } v; v.u = ((unsigned)s) << 16;
    return v.f;
}

// ---------------------------------------------------------------- small helpers

__global__ __launch_bounds__(256) void k_lin_in(const float* __restrict__ x,
    const float* __restrict__ W, const float* __restrict__ B, float* __restrict__ h)
{
    __shared__ float Ws[11 * 64];
    __shared__ float Bs[64];
    int t = threadIdx.x;
    for (int i = t; i < 11 * 64; i += 256) Ws[i] = W[i];
    if (t < 64) Bs[t] = B[t];
    __syncthreads();
    int i = blockIdx.x * 256 + t;
    if (i < Nn * 64) {
        int n = i >> 6, c = i & 63;
        float acc = Bs[c];
        #pragma unroll
        for (int k = 0; k < 11; k++) acc += x[n * 11 + k] * Ws[k * 64 + c];
        h[i] = acc;
    }
}

__global__ __launch_bounds__(256) void k_deg(const int* __restrict__ ei, float* __restrict__ deg)
{
    int e = blockIdx.x * 256 + threadIdx.x;
    if (e < Ee) atomicAdd(&deg[ei[Ee + e]], 1.f);
}

__global__ __launch_bounds__(256) void k_cnt(const int* __restrict__ batch, float* __restrict__ cnt)
{
    int n = blockIdx.x * 256 + threadIdx.x;
    if (n < Nn) atomicAdd(&cnt[batch[n]], 1.f);
}

// ------------------------------------------------- edge lin1 (133 -> 64) + stats
// R8 version (fp32 compute, bf16 output) — unchanged.

__global__ __launch_bounds__(256) void k_edge_lin1(
    const float* __restrict__ h, const float* __restrict__ p,
    const float* __restrict__ ea, const int* __restrict__ ei,
    const float* __restrict__ W, const float* __restrict__ B,
    u16* __restrict__ ybuf, float* __restrict__ stats_out)
{
    __shared__ float Ws[KIN * 64];
    __shared__ float Bs[64];
    __shared__ float in_t[KIN * ES];     // [k][e] transposed tile
    int t = threadIdx.x;
    for (int i = t; i < KIN * 64; i += 256) Ws[i] = W[i];
    if (t < 64) Bs[t] = B[t];
    int tx = t & 15, ty = t >> 4;
    int c = t & 63, eg = t >> 6;
    float ssum[4] = {0, 0, 0, 0}, ssq[4] = {0, 0, 0, 0};
    for (int tile = blockIdx.x; tile < Ee / 64; tile += gridDim.x) {
        int te = tile * 64;
        __syncthreads();
        for (int e = eg; e < 64; e += 4) {
            int sr = ei[te + e], ds = ei[Ee + te + e];
            in_t[c * ES + e]        = h[(size_t)ds * 64 + c];
            in_t[(64 + c) * ES + e] = h[(size_t)sr * 64 + c];
        }
        if (t < 64) {
            int e = t;
            int sr = ei[te + e], ds = ei[Ee + te + e];
            float dx = p[ds * 3 + 0] - p[sr * 3 + 0];
            float dy = p[ds * 3 + 1] - p[sr * 3 + 1];
            float dz = p[ds * 3 + 2] - p[sr * 3 + 2];
            in_t[128 * ES + e] = dx * dx + dy * dy + dz * dz;
            float4 a4 = *(const float4*)&ea[(size_t)(te + e) * 4];
            in_t[129 * ES + e] = a4.x;
            in_t[130 * ES + e] = a4.y;
            in_t[131 * ES + e] = a4.z;
            in_t[132 * ES + e] = a4.w;
        }
        __syncthreads();
        float acc[4][4];
        #pragma unroll
        for (int i = 0; i < 4; i++)
            #pragma unroll
            for (int j = 0; j < 4; j++) acc[i][j] = Bs[4 * ty + j];
        for (int k = 0; k < KIN; k++) {
            float av[4], wv[4];
            *(float4*)av = *(const float4*)&in_t[k * ES + 4 * tx];
            *(float4*)wv = *(const float4*)&Ws[k * 64 + 4 * ty];
            #pragma unroll
            for (int i = 0; i < 4; i++)
                #pragma unroll
                for (int j = 0; j < 4; j++)
                    acc[i][j] += av[i] * wv[j];
        }
        #pragma unroll
        for (int i = 0; i < 4; i++) {
            size_t e = (size_t)te + 4 * tx + i;
            ushort4 o;
            o.x = f2bf(acc[i][0]); o.y = f2bf(acc[i][1]);
            o.z = f2bf(acc[i][2]); o.w = f2bf(acc[i][3]);
            *(ushort4*)&ybuf[e * 64 + 4 * ty] = o;
            float r0 = bf2f(o.x), r1 = bf2f(o.y), r2 = bf2f(o.z), r3 = bf2f(o.w);
            ssum[0] += r0; ssum[1] += r1; ssum[2] += r2; ssum[3] += r3;
            ssq[0] += r0 * r0; ssq[1] += r1 * r1; ssq[2] += r2 * r2; ssq[3] += r3 * r3;
        }
    }
    #pragma unroll
    for (int j = 0; j < 4; j++) {
        float s = ssum[j], q = ssq[j];
        #pragma unroll
        for (int o2 = 1; o2 < 16; o2 <<= 1) { s += __shfl_xor(s, o2); q += __shfl_xor(q, o2); }
        if (tx == 0) {
            atomicAdd(&stats_out[4 * ty + j], s);
            atomicAdd(&stats_out[64 + 4 * ty + j], q);
        }
    }
}

// --------------------------- edge: bn+relu -> lin(64->64) via MFMA [+m_aggr] + stats
// EXACT R12 except OPERAND-SWAPPED MFMA: D = W^T x A^T, so each lane holds 4
// consecutive output channels of one edge -> aligned 8B ushort4 global stores
// (R8's fast store geometry). Fragments unchanged; only call order, bias init,
// store addressing, and stats bookkeeping differ. Single variable vs R12.

template<int AGGR>
__global__ __launch_bounds__(256) void k_edge_lin64(
    const float* __restrict__ stats_in, const float* __restrict__ gg,
    const float* __restrict__ be,
    const float* __restrict__ W, const float* __restrict__ B,
    const int* __restrict__ ei, float* __restrict__ magg,
    u16* __restrict__ ybuf, float* __restrict__ stats_out)
{
    __shared__ u16 At[64 * 72];          // A tile bf16, stride 72 u16 (144B)
    __shared__ u16 Wt[64 * 72];          // Wt[col][k] bf16, same stride
    __shared__ float As[64], Cs[64], Bs[64];
    int t = threadIdx.x;
    int lane = t & 63, w = t >> 6;
    int col16 = lane & 15, kg = lane >> 4;

    if (t < 64) {
        float mean = stats_in[t] * (1.f / Ee);
        float var  = stats_in[64 + t] * (1.f / Ee) - mean * mean;
        float a = gg[t] * rsqrtf(var + EPS);
        As[t] = a; Cs[t] = be[t] - mean * a; Bs[t] = B[t];
    }
    {   // build Wt: thread t -> col t&63, k in [(t>>6)*16, +16)
        int col = t & 63, k0 = (t >> 6) * 16;
        for (int k = k0; k < k0 + 16; k++)
            Wt[col * 72 + k] = f2bf(W[k * 64 + col]);
    }
    __syncthreads();

    // W fragments (tile-invariant): channel = 16*cb + col16, k = 8*kg + 32*half
    bf16x8 bfA[4], bfB[4];
    #pragma unroll
    for (int cb = 0; cb < 4; cb++) {
        const u16* wp = &Wt[(16 * cb + col16) * 72 + 8 * kg];
        bfA[cb] = *(const bf16x8*)&wp[0];
        bfB[cb] = *(const bf16x8*)&wp[32];
    }

    float ss[16], sq[16];
    #pragma unroll
    for (int i = 0; i < 16; i++) { ss[i] = 0.f; sq[i] = 0.f; }

    for (int tile = blockIdx.x; tile < Ee / 64; tile += gridDim.x) {
        int te = tile * 64;
        __syncthreads();                 // prev tile's At reads done
        // R8-pattern staging: per wave one row (64 lanes x 2B contiguous),
        // BN+relu per element, scalar u16 LDS write (conflict-free).
        for (int e = w; e < 64; e += 4) {
            float y = bf2f(ybuf[(size_t)(te + e) * 64 + lane]);
            At[e * 72 + lane] = f2bf(fmaxf(As[lane] * y + Cs[lane], 0.f));
        }
        __syncthreads();                 // At ready

        // edge fragments (B-operand now): edge = 16w + col16, k = 8*kg (+32)
        const u16* ap = &At[(16 * w + col16) * 72 + 8 * kg];
        bf16x8 a0 = *(const bf16x8*)&ap[0];
        bf16x8 a1 = *(const bf16x8*)&ap[32];
        #pragma unroll
        for (int cb = 0; cb < 4; cb++) {
            f32x4 acc;
            #pragma unroll
            for (int r = 0; r < 4; r++) acc[r] = Bs[16 * cb + 4 * kg + r];
            // SWAPPED: A-operand = W^T fragment, B-operand = edge fragment.
            acc = __builtin_amdgcn_mfma_f32_16x16x32_bf16(bfA[cb], a0, acc, 0, 0, 0);
            acc = __builtin_amdgcn_mfma_f32_16x16x32_bf16(bfB[cb], a1, acc, 0, 0, 0);
            // D[row=channel 4kg+r (+16cb), col=edge col16] -> lane owns 4
            // consecutive channels of edge te+16w+col16: aligned 8B store.
            ushort4 o;
            o.x = f2bf(acc[0]); o.y = f2bf(acc[1]);
            o.z = f2bf(acc[2]); o.w = f2bf(acc[3]);
            *(ushort4*)&ybuf[(size_t)(te + 16 * w + col16) * 64 + 16 * cb + 4 * kg] = o;
            float r0 = bf2f(o.x), r1 = bf2f(o.y), r2 = bf2f(o.z), r3 = bf2f(o.w);
            ss[4 * cb + 0] += r0; sq[4 * cb + 0] += r0 * r0;
            ss[4 * cb + 1] += r1; sq[4 * cb + 1] += r1 * r1;
            ss[4 * cb + 2] += r2; sq[4 * cb + 2] += r2 * r2;
            ss[4 * cb + 3] += r3; sq[4 * cb + 3] += r3 * r3;
        }
        if (AGGR) {                      // scatter m (bf16-rounded) into magg[dst]
            int dnode = ei[Ee + te + lane];
            const u16* mp = &At[lane * 72 + 16 * w];
            bf16x8 v0 = *(const bf16x8*)&mp[0];
            bf16x8 v1 = *(const bf16x8*)&mp[8];
            float* mg = &magg[(size_t)dnode * 64 + 16 * w];
            #pragma unroll
            for (int j = 0; j < 8; j++) {
                atomicAdd(&mg[j],     bf2f((u16)v0[j]));
                atomicAdd(&mg[8 + j], bf2f((u16)v1[j]));
            }
        }
    }
    // stats: lane holds channels 16*(i>>2) + 4*kg + (i&3); reduce over col16 lanes
    #pragma unroll
    for (int i = 0; i < 16; i++) {
        float s = ss[i], q = sq[i];
        s += __shfl_xor(s, 1); q += __shfl_xor(q, 1);
        s += __shfl_xor(s, 2); q += __shfl_xor(q, 2);
        s += __shfl_xor(s, 4); q += __shfl_xor(q, 4);
        s += __shfl_xor(s, 8); q += __shfl_xor(q, 8);
        if (col16 == 0) {
            int ch = 16 * (i >> 2) + 4 * kg + (i & 3);
            atomicAdd(&stats_out[ch], s);
            atomicAdd(&stats_out[64 + ch], q);
        }
    }
}

// ------------------------------- edge: bn+relu -> pos_lin2 (64->1) -> scatter pos update

__global__ __launch_bounds__(256) void k_pos2(
    const float* __restrict__ stats_in, const float* __restrict__ gg, const float* __restrict__ be,
    const float* __restrict__ W2, const float* __restrict__ B2,
    const float* __restrict__ p, const int* __restrict__ ei,
    const u16* __restrict__ ybuf, float* __restrict__ pagg)
{
    __shared__ float As[64], Cs[64], Ws[64];
    int t = threadIdx.x;
    if (t < 64) {
        float mean = stats_in[t] * (1.f / Ee);
        float var  = stats_in[64 + t] * (1.f / Ee) - mean * mean;
        float a = gg[t] * rsqrtf(var + EPS);
        As[t] = a; Cs[t] = be[t] - mean * a; Ws[t] = W2[t];
    }
    __syncthreads();
    int e = blockIdx.x * 256 + t;
    if (e >= Ee) return;
    float acc = B2[0];
    const u16* row = &ybuf[(size_t)e * 64];
    #pragma unroll
    for (int u = 0; u < 16; u++) {
        ushort4 y4 = *(const ushort4*)&row[4 * u];
        acc += fmaxf(As[4 * u + 0] * bf2f(y4.x) + Cs[4 * u + 0], 0.f) * Ws[4 * u + 0]
             + fmaxf(As[4 * u + 1] * bf2f(y4.y) + Cs[4 * u + 1], 0.f) * Ws[4 * u + 1]
             + fmaxf(As[4 * u + 2] * bf2f(y4.z) + Cs[4 * u + 2], 0.f) * Ws[4 * u + 2]
             + fmaxf(As[4 * u + 3] * bf2f(y4.w) + Cs[4 * u + 3], 0.f) * Ws[4 * u + 3];
    }
    int sr = ei[e], ds = ei[Ee + e];
    float dx = p[ds * 3 + 0] - p[sr * 3 + 0];
    float dy = p[ds * 3 + 1] - p[sr * 3 + 1];
    float dz = p[ds * 3 + 2] - p[sr * 3 + 2];
    atomicAdd(&pagg[ds * 3 + 0], dx * acc);
    atomicAdd(&pagg[ds * 3 + 1], dy * acc);
    atomicAdd(&pagg[ds * 3 + 2], dz * acc);
}

// ------------------------------------------- node: [h | m_aggr] (128 -> 64) + stats

__global__ __launch_bounds__(256) void k_node_lin1(
    const float* __restrict__ h, const float* __restrict__ magg,
    const float* __restrict__ W, const float* __restrict__ B,
    float* __restrict__ yn, float* __restrict__ stats_out)
{
    __shared__ float Ws[128 * 64];
    __shared__ float Bs[64];
    __shared__ float in_t[128 * ES];
    int t = threadIdx.x;
    for (int i = t; i < 128 * 64; i += 256) Ws[i] = W[i];
    if (t < 64) Bs[t] = B[t];
    int tx = t & 15, ty = t >> 4, c = t & 63, eg = t >> 6;
    float ssum[4] = {0, 0, 0, 0}, ssq[4] = {0, 0, 0, 0};
    int nT = (Nn + 63) / 64;
    for (int tile = blockIdx.x; tile < nT; tile += gridDim.x) {
        int te = tile * 64;
        __syncthreads();
        for (int e = eg; e < 64; e += 4) {
            int n = te + e;
            bool v = n < Nn;
            in_t[c * ES + e]        = v ? h[(size_t)n * 64 + c]    : 0.f;
            in_t[(64 + c) * ES + e] = v ? magg[(size_t)n * 64 + c] : 0.f;
        }
        __syncthreads();
        float acc[4][4];
        #pragma unroll
        for (int i = 0; i < 4; i++)
            #pragma unroll
            for (int j = 0; j < 4; j++) acc[i][j] = Bs[4 * ty + j];
        for (int k = 0; k < 128; k++) {
            float av[4], wv[4];
            *(float4*)av = *(const float4*)&in_t[k * ES + 4 * tx];
            *(float4*)wv = *(const float4*)&Ws[k * 64 + 4 * ty];
            #pragma unroll
            for (int i = 0; i < 4; i++)
                #pragma unroll
                for (int j = 0; j < 4; j++)
                    acc[i][j] += av[i] * wv[j];
        }
        #pragma unroll
        for (int i = 0; i < 4; i++) {
            int n = te + 4 * tx + i;
            if (n < Nn) {
                float4 o; o.x = acc[i][0]; o.y = acc[i][1]; o.z = acc[i][2]; o.w = acc[i][3];
                *(float4*)&yn[(size_t)n * 64 + 4 * ty] = o;
                #pragma unroll
                for (int j = 0; j < 4; j++) { ssum[j] += acc[i][j]; ssq[j] += acc[i][j] * acc[i][j]; }
            }
        }
    }
    #pragma unroll
    for (int j = 0; j < 4; j++) {
        float s = ssum[j], q = ssq[j];
        #pragma unroll
        for (int o2 = 1; o2 < 16; o2 <<= 1) { s += __shfl_xor(s, o2); q += __shfl_xor(q, o2); }
        if (tx == 0) {
            atomicAdd(&stats_out[4 * ty + j], s);
            atomicAdd(&stats_out[64 + 4 * ty + j], q);
        }
    }
}

// ------------------------------------------- node: bn+relu -> lin(64->64) + stats (in-place)

__global__ __launch_bounds__(256) void k_node_lin64(
    const float* __restrict__ stats_in, const float* __restrict__ gg, const float* __restrict__ be,
    const float* __restrict__ W, const float* __restrict__ B,
    float* __restrict__ yn, float* __restrict__ stats_out)
{
    __shared__ float Ws[64 * 64];
    __shared__ float As[64], Cs[64], Bs[64];
    __shared__ float in_t[64 * ES];
    int t = threadIdx.x;
    if (t < 64) {
        float mean = stats_in[t] * (1.f / Nn);
        float var  = stats_in[64 + t] * (1.f / Nn) - mean * mean;
        float a = gg[t] * rsqrtf(var + EPS);
        As[t] = a; Cs[t] = be[t] - mean * a; Bs[t] = B[t];
    }
    for (int i = t; i < 64 * 64; i += 256) Ws[i] = W[i];
    int tx = t & 15, ty = t >> 4, c = t & 63, eg = t >> 6;
    float ssum[4] = {0, 0, 0, 0}, ssq[4] = {0, 0, 0, 0};
    int nT = (Nn + 63) / 64;
    for (int tile = blockIdx.x; tile < nT; tile += gridDim.x) {
        int te = tile * 64;
        __syncthreads();
        for (int e = eg; e < 64; e += 4) {
            int n = te + e;
            float y = (n < Nn) ? yn[(size_t)n * 64 + c] : 0.f;
            in_t[c * ES + e] = fmaxf(As[c] * y + Cs[c], 0.f);
        }
        __syncthreads();
        float acc[4][4];
        #pragma unroll
        for (int i = 0; i < 4; i++)
            #pragma unroll
            for (int j = 0; j < 4; j++) acc[i][j] = Bs[4 * ty + j];
        for (int k = 0; k < 64; k++) {
            float av[4], wv[4];
            *(float4*)av = *(const float4*)&in_t[k * ES + 4 * tx];
            *(float4*)wv = *(const float4*)&Ws[k * 64 + 4 * ty];
            #pragma unroll
            for (int i = 0; i < 4; i++)
                #pragma unroll
                for (int j = 0; j < 4; j++)
                    acc[i][j] += av[i] * wv[j];
        }
        #pragma unroll
        for (int i = 0; i < 4; i++) {
            int n = te + 4 * tx + i;
            if (n < Nn) {
                float4 o; o.x = acc[i][0]; o.y = acc[i][1]; o.z = acc[i][2]; o.w = acc[i][3];
                *(float4*)&yn[(size_t)n * 64 + 4 * ty] = o;
                #pragma unroll
                for (int j = 0; j < 4; j++) { ssum[j] += acc[i][j]; ssq[j] += acc[i][j] * acc[i][j]; }
            }
        }
    }
    #pragma unroll
    for (int j = 0; j < 4; j++) {
        float s = ssum[j], q = ssq[j];
        #pragma unroll
        for (int o2 = 1; o2 < 16; o2 <<= 1) { s += __shfl_xor(s, o2); q += __shfl_xor(q, o2); }
        if (tx == 0) {
            atomicAdd(&stats_out[4 * ty + j], s);
            atomicAdd(&stats_out[64 + 4 * ty + j], q);
        }
    }
}

// ------------------------------------------- node: residual h += relu(bn(yn)); p update

__global__ __launch_bounds__(256) void k_node_update(
    const float* __restrict__ stats_in, const float* __restrict__ gg, const float* __restrict__ be,
    const float* __restrict__ yn, float* __restrict__ h,
    const float* __restrict__ p_in, float* __restrict__ p_out,
    const float* __restrict__ pagg, const float* __restrict__ deg)
{
    int i = blockIdx.x * 256 + threadIdx.x;
    if (i < Nn * 64) {
        int c = i & 63;
        float mean = stats_in[c] * (1.f / Nn);
        float var  = stats_in[64 + c] * (1.f / Nn) - mean * mean;
        float a = gg[c] * rsqrtf(var + EPS);
        float cc = be[c] - mean * a;
        h[i] += fmaxf(a * yn[i] + cc, 0.f);
    }
    if (i < Nn * 3) {
        float dg = fmaxf(deg[i / 3], 1.f);
        p_out[i] = p_in[i] + pagg[i] / dg;
    }
}

// ------------------------------------------- pooling + prediction head

__global__ __launch_bounds__(256) void k_pool(const int* __restrict__ batch,
    const float* __restrict__ h, float* __restrict__ pool)
{
    int i = blockIdx.x * 256 + threadIdx.x;
    if (i < Nn * 64) {
        int n = i >> 6, c = i & 63;
        atomicAdd(&pool[(size_t)batch[n] * 64 + c], h[i]);
    }
}

__global__ void k_out(const float* __restrict__ pool, const float* __restrict__ cnt,
    const float* __restrict__ W, const float* __restrict__ B, float* __restrict__ out)
{
    int g = threadIdx.x;
    if (g < 64) {
        float acc = 0.f;
        for (int c = 0; c < 64; c++) acc += pool[g * 64 + c] * W[c];
        out[g] = acc / fmaxf(cnt[g], 1.f) + B[0];
    }
}

// ---------------------------------------------------------------- launch

extern "C" void kernel_launch(void* const* d_in, const int* in_sizes, int n_in,
                              void* d_out, int out_size, void* d_ws, size_t ws_size,
                              hipStream_t stream)
{
    const float* x        = (const float*)d_in[0];
    const float* pos      = (const float*)d_in[1];
    const float* ea       = (const float*)d_in[2];
    const int*   ei       = (const int*)  d_in[3];
    const int*   batch    = (const int*)  d_in[4];
    const float* lin_in_w = (const float*)d_in[5];
    const float* lin_in_b = (const float*)d_in[6];
    const float* lin_pr_w = (const float*)d_in[7];
    const float* lin_pr_b = (const float*)d_in[8];
    const float* msg_w1   = (const float*)d_in[9];
    const float* msg_b1   = (const float*)d_in[10];
    const float* msg_g1   = (const float*)d_in[11];
    const float* msg_be1  = (const float*)d_in[12];
    const float* msg_w2   = (const float*)d_in[13];
    const float* msg_b2   = (const float*)d_in[14];
    const float* msg_g2   = (const float*)d_in[15];
    const float* msg_be2  = (const float*)d_in[16];
    const float* pos_w1   = (const float*)d_in[17];
    const float* pos_b1   = (const float*)d_in[18];
    const float* pos_g    = (const float*)d_in[19];
    const float* pos_be   = (const float*)d_in[20];
    const float* pos_w2   = (const float*)d_in[21];
    const float* pos_b2   = (const float*)d_in[22];
    const float* upd_w1   = (const float*)d_in[23];
    const float* upd_b1   = (const float*)d_in[24];
    const float* upd_g1   = (const float*)d_in[25];
    const float* upd_be1  = (const float*)d_in[26];
    const float* upd_w2   = (const float*)d_in[27];
    const float* upd_b2   = (const float*)d_in[28];
    const float* upd_g2   = (const float*)d_in[29];
    const float* upd_be2  = (const float*)d_in[30];
    float* out = (float*)d_out;

    float* ws = (float*)d_ws;
    size_t o = 0;
    float* h    = ws + o; o += (size_t)Nn * 64;
    u16*   ybuf = (u16*)(ws + o); o += (size_t)Ee * 64;  // bf16, uses half the slot
    float* yn   = ws + o; o += (size_t)Nn * 64;
    float* magg = ws + o; o += (size_t)Nn * 64;   // magg + pagg contiguous (one memset)
    float* pagg = ws + o; o += (size_t)Nn * 3;
    float* pws  = ws + o; o += (size_t)Nn * 3;
    float* stats= ws + o; o += 1280;              // stats..deg contiguous (one memset)
    float* pool = ws + o; o += 64 * 64;
    float* cnt  = ws + o; o += 64;
    float* deg  = ws + o; o += Nn;
    if (ws_size < o * sizeof(float)) return;

    hipMemsetAsync(stats, 0, (size_t)(1280 + 64 * 64 + 64 + Nn) * sizeof(float), stream);
    k_lin_in<<<(Nn * 64 + 255) / 256, 256, 0, stream>>>(x, lin_in_w, lin_in_b, h);
    k_deg<<<(Ee + 255) / 256, 256, 0, stream>>>(ei, deg);
    k_cnt<<<(Nn + 255) / 256, 256, 0, stream>>>(batch, cnt);

    for (int l = 0; l < 2; l++) {
        hipMemsetAsync(magg, 0, ((size_t)Nn * 64 + (size_t)Nn * 3) * sizeof(float), stream);
        const float* pc = (l == 0) ? pos : pws;
        float* st = stats + (size_t)l * 5 * 128;
        k_edge_lin1<<<512, 256, 0, stream>>>(h, pc, ea, ei,
            msg_w1 + (size_t)l * KIN * 64, msg_b1 + l * 64, ybuf, st + 0 * 128);
        k_edge_lin64<0><<<2048, 256, 0, stream>>>(st + 0 * 128, msg_g1 + l * 64, msg_be1 + l * 64,
            msg_w2 + (size_t)l * 64 * 64, msg_b2 + l * 64, ei, nullptr, ybuf, st + 1 * 128);
        k_edge_lin64<1><<<2048, 256, 0, stream>>>(st + 1 * 128, msg_g2 + l * 64, msg_be2 + l * 64,
            pos_w1 + (size_t)l * 64 * 64, pos_b1 + l * 64, ei, magg, ybuf, st + 2 * 128);
        k_pos2<<<(Ee + 255) / 256, 256, 0, stream>>>(st + 2 * 128, pos_g + l * 64, pos_be + l * 64,
            pos_w2 + l * 64, pos_b2 + l, pc, ei, ybuf, pagg);
        k_node_lin1<<<782, 256, 0, stream>>>(h, magg,
            upd_w1 + (size_t)l * 128 * 64, upd_b1 + l * 64, yn, st + 3 * 128);
        k_node_lin64<<<782, 256, 0, stream>>>(st + 3 * 128, upd_g1 + l * 64, upd_be1 + l * 64,
            upd_w2 + (size_t)l * 64 * 64, upd_b2 + l * 64, yn, st + 4 * 128);
        k_node_update<<<(Nn * 64 + 255) / 256, 256, 0, stream>>>(st + 4 * 128,
            upd_g2 + l * 64, upd_be2 + l * 64, yn, h, pc, pws, pagg, deg);
    }
    k_pool<<<(Nn * 64 + 255) / 256, 256, 0, stream>>>(batch, h, pool);
    k_out<<<1, 64, 0, stream>>>(pool, cnt, lin_pr_w, lin_pr_b, out);
}

// Round 14
// 4924.409 us; speedup vs baseline: 1.9557x; 1.9557x over previous
//
#include <hip/hip_runtime.h>

#define Nn 50000
#define Ee 800000
#define KIN 133      // 2*64 + 4 + 1
#define ES 68        // padded LDS tile stride (floats)
#define EPS 1e-5f

typedef unsigned short u16;
typedef __attribute__((ext_vector_type(8))) short bf16x8;
typedef __attribute__((ext_vector_type(4))) float f32x4;

// bf16 round-to-nearest-even pack/unpack
__device__ __forceinline__ u16 f2bf(float f) {
    union { float f; unsigned u; } v; v.f = f;
    unsigned r = (v.u + 0x7FFFu + ((v.u >> 16) & 1u)) >> 16;
    return (u16)r;
}
__device__ __forceinline__ float bf2f(u16 s) {
    union { unsigned u; float f; } v; v.u = ((unsigned)s) << 16;
    return v.f;
}

// ---------------------------------------------------------------- small helpers

__global__ __launch_bounds__(256) void k_lin_in(const float* __restrict__ x,
    const float* __restrict__ W, const float* __restrict__ B, float* __restrict__ h)
{
    __shared__ float Ws[11 * 64];
    __shared__ float Bs[64];
    int t = threadIdx.x;
    for (int i = t; i < 11 * 64; i += 256) Ws[i] = W[i];
    if (t < 64) Bs[t] = B[t];
    __syncthreads();
    int i = blockIdx.x * 256 + t;
    if (i < Nn * 64) {
        int n = i >> 6, c = i & 63;
        float acc = Bs[c];
        #pragma unroll
        for (int k = 0; k < 11; k++) acc += x[n * 11 + k] * Ws[k * 64 + c];
        h[i] = acc;
    }
}

__global__ __launch_bounds__(256) void k_deg(const int* __restrict__ ei, float* __restrict__ deg)
{
    int e = blockIdx.x * 256 + threadIdx.x;
    if (e < Ee) atomicAdd(&deg[ei[Ee + e]], 1.f);
}

__global__ __launch_bounds__(256) void k_cnt(const int* __restrict__ batch, float* __restrict__ cnt)
{
    int n = blockIdx.x * 256 + threadIdx.x;
    if (n < Nn) atomicAdd(&cnt[batch[n]], 1.f);
}

// ------------------------------------------------- edge lin1 (133 -> 64) + stats
// R8 version (fp32 compute, bf16 output) — unchanged.

__global__ __launch_bounds__(256) void k_edge_lin1(
    const float* __restrict__ h, const float* __restrict__ p,
    const float* __restrict__ ea, const int* __restrict__ ei,
    const float* __restrict__ W, const float* __restrict__ B,
    u16* __restrict__ ybuf, float* __restrict__ stats_out)
{
    __shared__ float Ws[KIN * 64];
    __shared__ float Bs[64];
    __shared__ float in_t[KIN * ES];     // [k][e] transposed tile
    int t = threadIdx.x;
    for (int i = t; i < KIN * 64; i += 256) Ws[i] = W[i];
    if (t < 64) Bs[t] = B[t];
    int tx = t & 15, ty = t >> 4;
    int c = t & 63, eg = t >> 6;
    float ssum[4] = {0, 0, 0, 0}, ssq[4] = {0, 0, 0, 0};
    for (int tile = blockIdx.x; tile < Ee / 64; tile += gridDim.x) {
        int te = tile * 64;
        __syncthreads();
        for (int e = eg; e < 64; e += 4) {
            int sr = ei[te + e], ds = ei[Ee + te + e];
            in_t[c * ES + e]        = h[(size_t)ds * 64 + c];
            in_t[(64 + c) * ES + e] = h[(size_t)sr * 64 + c];
        }
        if (t < 64) {
            int e = t;
            int sr = ei[te + e], ds = ei[Ee + te + e];
            float dx = p[ds * 3 + 0] - p[sr * 3 + 0];
            float dy = p[ds * 3 + 1] - p[sr * 3 + 1];
            float dz = p[ds * 3 + 2] - p[sr * 3 + 2];
            in_t[128 * ES + e] = dx * dx + dy * dy + dz * dz;
            float4 a4 = *(const float4*)&ea[(size_t)(te + e) * 4];
            in_t[129 * ES + e] = a4.x;
            in_t[130 * ES + e] = a4.y;
            in_t[131 * ES + e] = a4.z;
            in_t[132 * ES + e] = a4.w;
        }
        __syncthreads();
        float acc[4][4];
        #pragma unroll
        for (int i = 0; i < 4; i++)
            #pragma unroll
            for (int j = 0; j < 4; j++) acc[i][j] = Bs[4 * ty + j];
        for (int k = 0; k < KIN; k++) {
            float av[4], wv[4];
            *(float4*)av = *(const float4*)&in_t[k * ES + 4 * tx];
            *(float4*)wv = *(const float4*)&Ws[k * 64 + 4 * ty];
            #pragma unroll
            for (int i = 0; i < 4; i++)
                #pragma unroll
                for (int j = 0; j < 4; j++)
                    acc[i][j] += av[i] * wv[j];
        }
        #pragma unroll
        for (int i = 0; i < 4; i++) {
            size_t e = (size_t)te + 4 * tx + i;
            ushort4 o;
            o.x = f2bf(acc[i][0]); o.y = f2bf(acc[i][1]);
            o.z = f2bf(acc[i][2]); o.w = f2bf(acc[i][3]);
            *(ushort4*)&ybuf[e * 64 + 4 * ty] = o;
            float r0 = bf2f(o.x), r1 = bf2f(o.y), r2 = bf2f(o.z), r3 = bf2f(o.w);
            ssum[0] += r0; ssum[1] += r1; ssum[2] += r2; ssum[3] += r3;
            ssq[0] += r0 * r0; ssq[1] += r1 * r1; ssq[2] += r2 * r2; ssq[3] += r3 * r3;
        }
    }
    #pragma unroll
    for (int j = 0; j < 4; j++) {
        float s = ssum[j], q = ssq[j];
        #pragma unroll
        for (int o2 = 1; o2 < 16; o2 <<= 1) { s += __shfl_xor(s, o2); q += __shfl_xor(q, o2); }
        if (tx == 0) {
            atomicAdd(&stats_out[4 * ty + j], s);
            atomicAdd(&stats_out[64 + 4 * ty + j], q);
        }
    }
}

// ----------------- edge lin64, SCALAR variant (R8 exact — proven fast)

template<int AGGR>
__global__ __launch_bounds__(256) void k_edge_lin64_s(
    const float* __restrict__ stats_in, const float* __restrict__ gg,
    const float* __restrict__ be,
    const float* __restrict__ W, const float* __restrict__ B,
    const int* __restrict__ ei, float* __restrict__ magg,
    u16* __restrict__ ybuf, float* __restrict__ stats_out)
{
    __shared__ float Ws[64 * 64];
    __shared__ float As[64], Cs[64], Bs[64];
    __shared__ float in_t[64 * ES];
    int t = threadIdx.x;
    if (t < 64) {
        float mean = stats_in[t] * (1.f / Ee);
        float var  = stats_in[64 + t] * (1.f / Ee) - mean * mean;
        float a = gg[t] * rsqrtf(var + EPS);
        As[t] = a; Cs[t] = be[t] - mean * a; Bs[t] = B[t];
    }
    for (int i = t; i < 64 * 64; i += 256) Ws[i] = W[i];
    int tx = t & 15, ty = t >> 4;
    int c = t & 63, eg = t >> 6;
    float ssum[4] = {0, 0, 0, 0}, ssq[4] = {0, 0, 0, 0};
    for (int tile = blockIdx.x; tile < Ee / 64; tile += gridDim.x) {
        int te = tile * 64;
        __syncthreads();
        for (int e = eg; e < 64; e += 4) {
            float y = bf2f(ybuf[(size_t)(te + e) * 64 + c]);
            in_t[c * ES + e] = fmaxf(As[c] * y + Cs[c], 0.f);
        }
        __syncthreads();
        float acc[4][4];
        #pragma unroll
        for (int i = 0; i < 4; i++)
            #pragma unroll
            for (int j = 0; j < 4; j++) acc[i][j] = Bs[4 * ty + j];
        for (int k = 0; k < 64; k++) {
            float av[4], wv[4];
            *(float4*)av = *(const float4*)&in_t[k * ES + 4 * tx];
            *(float4*)wv = *(const float4*)&Ws[k * 64 + 4 * ty];
            #pragma unroll
            for (int i = 0; i < 4; i++)
                #pragma unroll
                for (int j = 0; j < 4; j++)
                    acc[i][j] += av[i] * wv[j];
        }
        if (AGGR) {
            for (int e = eg; e < 64; e += 4) {
                int ds = ei[Ee + te + e];
                atomicAdd(&magg[(size_t)ds * 64 + c], in_t[c * ES + e]);
            }
        }
        #pragma unroll
        for (int i = 0; i < 4; i++) {
            size_t e = (size_t)te + 4 * tx + i;
            ushort4 o;
            o.x = f2bf(acc[i][0]); o.y = f2bf(acc[i][1]);
            o.z = f2bf(acc[i][2]); o.w = f2bf(acc[i][3]);
            *(ushort4*)&ybuf[e * 64 + 4 * ty] = o;
            float r0 = bf2f(o.x), r1 = bf2f(o.y), r2 = bf2f(o.z), r3 = bf2f(o.w);
            ssum[0] += r0; ssum[1] += r1; ssum[2] += r2; ssum[3] += r3;
            ssq[0] += r0 * r0; ssq[1] += r1 * r1; ssq[2] += r2 * r2; ssq[3] += r3 * r3;
        }
    }
    #pragma unroll
    for (int j = 0; j < 4; j++) {
        float s = ssum[j], q = ssq[j];
        #pragma unroll
        for (int o2 = 1; o2 < 16; o2 <<= 1) { s += __shfl_xor(s, o2); q += __shfl_xor(q, o2); }
        if (tx == 0) {
            atomicAdd(&stats_out[4 * ty + j], s);
            atomicAdd(&stats_out[64 + 4 * ty + j], q);
        }
    }
}

// ----------------- edge lin64, MFMA variant (R12 body exact; launched @1024)

template<int AGGR>
__global__ __launch_bounds__(256) void k_edge_lin64_m(
    const float* __restrict__ stats_in, const float* __restrict__ gg,
    const float* __restrict__ be,
    const float* __restrict__ W, const float* __restrict__ B,
    const int* __restrict__ ei, float* __restrict__ magg,
    u16* __restrict__ ybuf, float* __restrict__ stats_out)
{
    __shared__ u16 At[64 * 72];
    __shared__ u16 Wt[64 * 72];
    __shared__ float As[64], Cs[64], Bs[64];
    int t = threadIdx.x;
    int lane = t & 63, w = t >> 6;
    int col16 = lane & 15, kg = lane >> 4;

    if (t < 64) {
        float mean = stats_in[t] * (1.f / Ee);
        float var  = stats_in[64 + t] * (1.f / Ee) - mean * mean;
        float a = gg[t] * rsqrtf(var + EPS);
        As[t] = a; Cs[t] = be[t] - mean * a; Bs[t] = B[t];
    }
    {
        int col = t & 63, k0 = (t >> 6) * 16;
        for (int k = k0; k < k0 + 16; k++)
            Wt[col * 72 + k] = f2bf(W[k * 64 + col]);
    }
    __syncthreads();

    bf16x8 bfA[4], bfB[4];
    #pragma unroll
    for (int cb = 0; cb < 4; cb++) {
        const u16* wp = &Wt[(16 * cb + col16) * 72 + 8 * kg];
        bfA[cb] = *(const bf16x8*)&wp[0];
        bfB[cb] = *(const bf16x8*)&wp[32];
    }

    float ssum[4] = {0, 0, 0, 0}, ssq[4] = {0, 0, 0, 0};

    for (int tile = blockIdx.x; tile < Ee / 64; tile += gridDim.x) {
        int te = tile * 64;
        __syncthreads();
        for (int e = w; e < 64; e += 4) {
            float y = bf2f(ybuf[(size_t)(te + e) * 64 + lane]);
            At[e * 72 + lane] = f2bf(fmaxf(As[lane] * y + Cs[lane], 0.f));
        }
        __syncthreads();

        const u16* ap = &At[(16 * w + col16) * 72 + 8 * kg];
        bf16x8 a0 = *(const bf16x8*)&ap[0];
        bf16x8 a1 = *(const bf16x8*)&ap[32];
        #pragma unroll
        for (int cb = 0; cb < 4; cb++) {
            f32x4 acc;
            float bv = Bs[16 * cb + col16];
            acc[0] = bv; acc[1] = bv; acc[2] = bv; acc[3] = bv;
            acc = __builtin_amdgcn_mfma_f32_16x16x32_bf16(a0, bfA[cb], acc, 0, 0, 0);
            acc = __builtin_amdgcn_mfma_f32_16x16x32_bf16(a1, bfB[cb], acc, 0, 0, 0);
            #pragma unroll
            for (int r = 0; r < 4; r++) {
                u16 ob = f2bf(acc[r]);
                int erow = te + 16 * w + 4 * kg + r;
                ybuf[(size_t)erow * 64 + 16 * cb + col16] = ob;
                float rv = bf2f(ob);
                ssum[cb] += rv; ssq[cb] += rv * rv;
            }
        }
        if (AGGR) {
            int dnode = ei[Ee + te + lane];
            const u16* mp = &At[lane * 72 + 16 * w];
            bf16x8 v0 = *(const bf16x8*)&mp[0];
            bf16x8 v1 = *(const bf16x8*)&mp[8];
            float* mg = &magg[(size_t)dnode * 64 + 16 * w];
            #pragma unroll
            for (int j = 0; j < 8; j++) {
                atomicAdd(&mg[j],     bf2f((u16)v0[j]));
                atomicAdd(&mg[8 + j], bf2f((u16)v1[j]));
            }
        }
    }
    #pragma unroll
    for (int cb = 0; cb < 4; cb++) {
        float s = ssum[cb], q = ssq[cb];
        s += __shfl_xor(s, 16); q += __shfl_xor(q, 16);
        s += __shfl_xor(s, 32); q += __shfl_xor(q, 32);
        if (kg == 0) {
            atomicAdd(&stats_out[16 * cb + col16], s);
            atomicAdd(&stats_out[64 + 16 * cb + col16], q);
        }
    }
}

// ------------------------------- edge: bn+relu -> pos_lin2 (64->1) -> scatter pos update

__global__ __launch_bounds__(256) void k_pos2(
    const float* __restrict__ stats_in, const float* __restrict__ gg, const float* __restrict__ be,
    const float* __restrict__ W2, const float* __restrict__ B2,
    const float* __restrict__ p, const int* __restrict__ ei,
    const u16* __restrict__ ybuf, float* __restrict__ pagg)
{
    __shared__ float As[64], Cs[64], Ws[64];
    int t = threadIdx.x;
    if (t < 64) {
        float mean = stats_in[t] * (1.f / Ee);
        float var  = stats_in[64 + t] * (1.f / Ee) - mean * mean;
        float a = gg[t] * rsqrtf(var + EPS);
        As[t] = a; Cs[t] = be[t] - mean * a; Ws[t] = W2[t];
    }
    __syncthreads();
    int e = blockIdx.x * 256 + t;
    if (e >= Ee) return;
    float acc = B2[0];
    const u16* row = &ybuf[(size_t)e * 64];
    #pragma unroll
    for (int u = 0; u < 16; u++) {
        ushort4 y4 = *(const ushort4*)&row[4 * u];
        acc += fmaxf(As[4 * u + 0] * bf2f(y4.x) + Cs[4 * u + 0], 0.f) * Ws[4 * u + 0]
             + fmaxf(As[4 * u + 1] * bf2f(y4.y) + Cs[4 * u + 1], 0.f) * Ws[4 * u + 1]
             + fmaxf(As[4 * u + 2] * bf2f(y4.z) + Cs[4 * u + 2], 0.f) * Ws[4 * u + 2]
             + fmaxf(As[4 * u + 3] * bf2f(y4.w) + Cs[4 * u + 3], 0.f) * Ws[4 * u + 3];
    }
    int sr = ei[e], ds = ei[Ee + e];
    float dx = p[ds * 3 + 0] - p[sr * 3 + 0];
    float dy = p[ds * 3 + 1] - p[sr * 3 + 1];
    float dz = p[ds * 3 + 2] - p[sr * 3 + 2];
    atomicAdd(&pagg[ds * 3 + 0], dx * acc);
    atomicAdd(&pagg[ds * 3 + 1], dy * acc);
    atomicAdd(&pagg[ds * 3 + 2], dz * acc);
}

// ------------------------------------------- node: [h | m_aggr] (128 -> 64) + stats

__global__ __launch_bounds__(256) void k_node_lin1(
    const float* __restrict__ h, const float* __restrict__ magg,
    const float* __restrict__ W, const float* __restrict__ B,
    float* __restrict__ yn, float* __restrict__ stats_out)
{
    __shared__ float Ws[128 * 64];
    __shared__ float Bs[64];
    __shared__ float in_t[128 * ES];
    int t = threadIdx.x;
    for (int i = t; i < 128 * 64; i += 256) Ws[i] = W[i];
    if (t < 64) Bs[t] = B[t];
    int tx = t & 15, ty = t >> 4, c = t & 63, eg = t >> 6;
    float ssum[4] = {0, 0, 0, 0}, ssq[4] = {0, 0, 0, 0};
    int nT = (Nn + 63) / 64;
    for (int tile = blockIdx.x; tile < nT; tile += gridDim.x) {
        int te = tile * 64;
        __syncthreads();
        for (int e = eg; e < 64; e += 4) {
            int n = te + e;
            bool v = n < Nn;
            in_t[c * ES + e]        = v ? h[(size_t)n * 64 + c]    : 0.f;
            in_t[(64 + c) * ES + e] = v ? magg[(size_t)n * 64 + c] : 0.f;
        }
        __syncthreads();
        float acc[4][4];
        #pragma unroll
        for (int i = 0; i < 4; i++)
            #pragma unroll
            for (int j = 0; j < 4; j++) acc[i][j] = Bs[4 * ty + j];
        for (int k = 0; k < 128; k++) {
            float av[4], wv[4];
            *(float4*)av = *(const float4*)&in_t[k * ES + 4 * tx];
            *(float4*)wv = *(const float4*)&Ws[k * 64 + 4 * ty];
            #pragma unroll
            for (int i = 0; i < 4; i++)
                #pragma unroll
                for (int j = 0; j < 4; j++)
                    acc[i][j] += av[i] * wv[j];
        }
        #pragma unroll
        for (int i = 0; i < 4; i++) {
            int n = te + 4 * tx + i;
            if (n < Nn) {
                float4 o; o.x = acc[i][0]; o.y = acc[i][1]; o.z = acc[i][2]; o.w = acc[i][3];
                *(float4*)&yn[(size_t)n * 64 + 4 * ty] = o;
                #pragma unroll
                for (int j = 0; j < 4; j++) { ssum[j] += acc[i][j]; ssq[j] += acc[i][j] * acc[i][j]; }
            }
        }
    }
    #pragma unroll
    for (int j = 0; j < 4; j++) {
        float s = ssum[j], q = ssq[j];
        #pragma unroll
        for (int o2 = 1; o2 < 16; o2 <<= 1) { s += __shfl_xor(s, o2); q += __shfl_xor(q, o2); }
        if (tx == 0) {
            atomicAdd(&stats_out[4 * ty + j], s);
            atomicAdd(&stats_out[64 + 4 * ty + j], q);
        }
    }
}

// ------------------------------------------- node: bn+relu -> lin(64->64) + stats (in-place)

__global__ __launch_bounds__(256) void k_node_lin64(
    const float* __restrict__ stats_in, const float* __restrict__ gg, const float* __restrict__ be,
    const float* __restrict__ W, const float* __restrict__ B,
    float* __restrict__ yn, float* __restrict__ stats_out)
{
    __shared__ float Ws[64 * 64];
    __shared__ float As[64], Cs[64], Bs[64];
    __shared__ float in_t[64 * ES];
    int t = threadIdx.x;
    if (t < 64) {
        float mean = stats_in[t] * (1.f / Nn);
        float var  = stats_in[64 + t] * (1.f / Nn) - mean * mean;
        float a = gg[t] * rsqrtf(var + EPS);
        As[t] = a; Cs[t] = be[t] - mean * a; Bs[t] = B[t];
    }
    for (int i = t; i < 64 * 64; i += 256) Ws[i] = W[i];
    int tx = t & 15, ty = t >> 4, c = t & 63, eg = t >> 6;
    float ssum[4] = {0, 0, 0, 0}, ssq[4] = {0, 0, 0, 0};
    int nT = (Nn + 63) / 64;
    for (int tile = blockIdx.x; tile < nT; tile += gridDim.x) {
        int te = tile * 64;
        __syncthreads();
        for (int e = eg; e < 64; e += 4) {
            int n = te + e;
            float y = (n < Nn) ? yn[(size_t)n * 64 + c] : 0.f;
            in_t[c * ES + e] = fmaxf(As[c] * y + Cs[c], 0.f);
        }
        __syncthreads();
        float acc[4][4];
        #pragma unroll
        for (int i = 0; i < 4; i++)
            #pragma unroll
            for (int j = 0; j < 4; j++) acc[i][j] = Bs[4 * ty + j];
        for (int k = 0; k < 64; k++) {
            float av[4], wv[4];
            *(float4*)av = *(const float4*)&in_t[k * ES + 4 * tx];
            *(float4*)wv = *(const float4*)&Ws[k * 64 + 4 * ty];
            #pragma unroll
            for (int i = 0; i < 4; i++)
                #pragma unroll
                for (int j = 0; j < 4; j++)
                    acc[i][j] += av[i] * wv[j];
        }
        #pragma unroll
        for (int i = 0; i < 4; i++) {
            int n = te + 4 * tx + i;
            if (n < Nn) {
                float4 o; o.x = acc[i][0]; o.y = acc[i][1]; o.z = acc[i][2]; o.w = acc[i][3];
                *(float4*)&yn[(size_t)n * 64 + 4 * ty] = o;
                #pragma unroll
                for (int j = 0; j < 4; j++) { ssum[j] += acc[i][j]; ssq[j] += acc[i][j] * acc[i][j]; }
            }
        }
    }
    #pragma unroll
    for (int j = 0; j < 4; j++) {
        float s = ssum[j], q = ssq[j];
        #pragma unroll
        for (int o2 = 1; o2 < 16; o2 <<= 1) { s += __shfl_xor(s, o2); q += __shfl_xor(q, o2); }
        if (tx == 0) {
            atomicAdd(&stats_out[4 * ty + j], s);
            atomicAdd(&stats_out[64 + 4 * ty + j], q);
        }
    }
}

// ------------------------------------------- node: residual h += relu(bn(yn)); p update

__global__ __launch_bounds__(256) void k_node_update(
    const float* __restrict__ stats_in, const float* __restrict__ gg, const float* __restrict__ be,
    const float* __restrict__ yn, float* __restrict__ h,
    const float* __restrict__ p_in, float* __restrict__ p_out,
    const float* __restrict__ pagg, const float* __restrict__ deg)
{
    int i = blockIdx.x * 256 + threadIdx.x;
    if (i < Nn * 64) {
        int c = i & 63;
        float mean = stats_in[c] * (1.f / Nn);
        float var  = stats_in[64 + c] * (1.f / Nn) - mean * mean;
        float a = gg[c] * rsqrtf(var + EPS);
        float cc = be[c] - mean * a;
        h[i] += fmaxf(a * yn[i] + cc, 0.f);
    }
    if (i < Nn * 3) {
        float dg = fmaxf(deg[i / 3], 1.f);
        p_out[i] = p_in[i] + pagg[i] / dg;
    }
}

// ------------------------------------------- pooling + prediction head

__global__ __launch_bounds__(256) void k_pool(const int* __restrict__ batch,
    const float* __restrict__ h, float* __restrict__ pool)
{
    int i = blockIdx.x * 256 + threadIdx.x;
    if (i < Nn * 64) {
        int n = i >> 6, c = i & 63;
        atomicAdd(&pool[(size_t)batch[n] * 64 + c], h[i]);
    }
}

__global__ void k_out(const float* __restrict__ pool, const float* __restrict__ cnt,
    const float* __restrict__ W, const float* __restrict__ B, float* __restrict__ out)
{
    int g = threadIdx.x;
    if (g < 64) {
        float acc = 0.f;
        for (int c = 0; c < 64; c++) acc += pool[g * 64 + c] * W[c];
        out[g] = acc / fmaxf(cnt[g], 1.f) + B[0];
    }
}

// ---------------------------------------------------------------- launch

extern "C" void kernel_launch(void* const* d_in, const int* in_sizes, int n_in,
                              void* d_out, int out_size, void* d_ws, size_t ws_size,
                              hipStream_t stream)
{
    const float* x        = (const float*)d_in[0];
    const float* pos      = (const float*)d_in[1];
    const float* ea       = (const float*)d_in[2];
    const int*   ei       = (const int*)  d_in[3];
    const int*   batch    = (const int*)  d_in[4];
    const float* lin_in_w = (const float*)d_in[5];
    const float* lin_in_b = (const float*)d_in[6];
    const float* lin_pr_w = (const float*)d_in[7];
    const float* lin_pr_b = (const float*)d_in[8];
    const float* msg_w1   = (const float*)d_in[9];
    const float* msg_b1   = (const float*)d_in[10];
    const float* msg_g1   = (const float*)d_in[11];
    const float* msg_be1  = (const float*)d_in[12];
    const float* msg_w2   = (const float*)d_in[13];
    const float* msg_b2   = (const float*)d_in[14];
    const float* msg_g2   = (const float*)d_in[15];
    const float* msg_be2  = (const float*)d_in[16];
    const float* pos_w1   = (const float*)d_in[17];
    const float* pos_b1   = (const float*)d_in[18];
    const float* pos_g    = (const float*)d_in[19];
    const float* pos_be   = (const float*)d_in[20];
    const float* pos_w2   = (const float*)d_in[21];
    const float* pos_b2   = (const float*)d_in[22];
    const float* upd_w1   = (const float*)d_in[23];
    const float* upd_b1   = (const float*)d_in[24];
    const float* upd_g1   = (const float*)d_in[25];
    const float* upd_be1  = (const float*)d_in[26];
    const float* upd_w2   = (const float*)d_in[27];
    const float* upd_b2   = (const float*)d_in[28];
    const float* upd_g2   = (const float*)d_in[29];
    const float* upd_be2  = (const float*)d_in[30];
    float* out = (float*)d_out;

    float* ws = (float*)d_ws;
    size_t o = 0;
    float* h    = ws + o; o += (size_t)Nn * 64;
    u16*   ybuf = (u16*)(ws + o); o += (size_t)Ee * 64;  // bf16, uses half the slot
    float* yn   = ws + o; o += (size_t)Nn * 64;
    float* magg = ws + o; o += (size_t)Nn * 64;   // magg + pagg contiguous (one memset)
    float* pagg = ws + o; o += (size_t)Nn * 3;
    float* pws  = ws + o; o += (size_t)Nn * 3;
    float* stats= ws + o; o += 1280;              // stats..deg contiguous (one memset)
    float* pool = ws + o; o += 64 * 64;
    float* cnt  = ws + o; o += 64;
    float* deg  = ws + o; o += Nn;
    if (ws_size < o * sizeof(float)) return;

    hipMemsetAsync(stats, 0, (size_t)(1280 + 64 * 64 + 64 + Nn) * sizeof(float), stream);
    k_lin_in<<<(Nn * 64 + 255) / 256, 256, 0, stream>>>(x, lin_in_w, lin_in_b, h);
    k_deg<<<(Ee + 255) / 256, 256, 0, stream>>>(ei, deg);
    k_cnt<<<(Nn + 255) / 256, 256, 0, stream>>>(batch, cnt);

    for (int l = 0; l < 2; l++) {
        hipMemsetAsync(magg, 0, ((size_t)Nn * 64 + (size_t)Nn * 3) * sizeof(float), stream);
        const float* pc = (l == 0) ? pos : pws;
        float* st = stats + (size_t)l * 5 * 128;
        k_edge_lin1<<<512, 256, 0, stream>>>(h, pc, ea, ei,
            msg_w1 + (size_t)l * KIN * 64, msg_b1 + l * 64, ybuf, st + 0 * 128);
        if (l == 0) {   // A: MFMA variant at grid 1024
            k_edge_lin64_m<0><<<1024, 256, 0, stream>>>(st + 0 * 128, msg_g1, msg_be1,
                msg_w2, msg_b2, ei, nullptr, ybuf, st + 1 * 128);
            k_edge_lin64_m<1><<<1024, 256, 0, stream>>>(st + 1 * 128, msg_g2, msg_be2,
                pos_w1, pos_b1, ei, magg, ybuf, st + 2 * 128);
        } else {        // B: scalar variant (R8 exact)
            k_edge_lin64_s<0><<<1024, 256, 0, stream>>>(st + 0 * 128, msg_g1 + 64, msg_be1 + 64,
                msg_w2 + 64 * 64, msg_b2 + 64, ei, nullptr, ybuf, st + 1 * 128);
            k_edge_lin64_s<1><<<1024, 256, 0, stream>>>(st + 1 * 128, msg_g2 + 64, msg_be2 + 64,
                pos_w1 + 64 * 64, pos_b1 + 64, ei, magg, ybuf, st + 2 * 128);
        }
        k_pos2<<<(Ee + 255) / 256, 256, 0, stream>>>(st + 2 * 128, pos_g + l * 64, pos_be + l * 64,
            pos_w2 + l * 64, pos_b2 + l, pc, ei, ybuf, pagg);
        k_node_lin1<<<782, 256, 0, stream>>>(h, magg,
            upd_w1 + (size_t)l * 128 * 64, upd_b1 + l * 64, yn, st + 3 * 128);
        k_node_lin64<<<782, 256, 0, stream>>>(st + 3 * 128, upd_g1 + l * 64, upd_be1 + l * 64,
            upd_w2 + (size_t)l * 64 * 64, upd_b2 + l * 64, yn, st + 4 * 128);
        k_node_update<<<(Nn * 64 + 255) / 256, 256, 0, stream>>>(st + 4 * 128,
            upd_g2 + l * 64, upd_be2 + l * 64, yn, h, pc, pws, pagg, deg);
    }
    k_pool<<<(Nn * 64 + 255) / 256, 256, 0, stream>>>(batch, h, pool);
    k_out<<<1, 64, 0, stream>>>(pool, cnt, lin_pr_w, lin_pr_b, out);
}

// Round 15
// 2470.664 us; speedup vs baseline: 3.8981x; 1.9932x over previous
//
#include <hip/hip_runtime.h>

#define Nn 50000
#define Ee 800000
#define KIN 133      // 2*64 + 4 + 1
#define ES 68        // padded LDS tile stride (floats)
#define EPS 1e-5f

typedef unsigned short u16;

// bf16 round-to-nearest-even pack/unpack
__device__ __forceinline__ u16 f2bf(float f) {
    union { float f; unsigned u; } v; v.f = f;
    unsigned r = (v.u + 0x7FFFu + ((v.u >> 16) & 1u)) >> 16;
    return (u16)r;
}
__device__ __forceinline__ float bf2f(u16 s) {
    union { unsigned u; float f; } v; v.u = ((unsigned)s) << 16;
    return v.f;
}

// ---------------------------------------------------------------- small helpers

__global__ __launch_bounds__(256) void k_lin_in(const float* __restrict__ x,
    const float* __restrict__ W, const float* __restrict__ B, float* __restrict__ h)
{
    __shared__ float Ws[11 * 64];
    __shared__ float Bs[64];
    int t = threadIdx.x;
    for (int i = t; i < 11 * 64; i += 256) Ws[i] = W[i];
    if (t < 64) Bs[t] = B[t];
    __syncthreads();
    int i = blockIdx.x * 256 + t;
    if (i < Nn * 64) {
        int n = i >> 6, c = i & 63;
        float acc = Bs[c];
        #pragma unroll
        for (int k = 0; k < 11; k++) acc += x[n * 11 + k] * Ws[k * 64 + c];
        h[i] = acc;
    }
}

__global__ __launch_bounds__(256) void k_deg(const int* __restrict__ ei, float* __restrict__ deg)
{
    int e = blockIdx.x * 256 + threadIdx.x;
    if (e < Ee) atomicAdd(&deg[ei[Ee + e]], 1.f);
}

__global__ __launch_bounds__(256) void k_cnt(const int* __restrict__ batch, float* __restrict__ cnt)
{
    int n = blockIdx.x * 256 + threadIdx.x;
    if (n < Nn) atomicAdd(&cnt[batch[n]], 1.f);
}

// ------------------------------------------------- edge lin1 (133 -> 64) + stats
// fp32 compute, bf16 output (stats from rounded values).

__global__ __launch_bounds__(256) void k_edge_lin1(
    const float* __restrict__ h, const float* __restrict__ p,
    const float* __restrict__ ea, const int* __restrict__ ei,
    const float* __restrict__ W, const float* __restrict__ B,
    u16* __restrict__ ybuf, float* __restrict__ stats_out)
{
    __shared__ float Ws[KIN * 64];
    __shared__ float Bs[64];
    __shared__ float in_t[KIN * ES];     // [k][e] transposed tile
    int t = threadIdx.x;
    for (int i = t; i < KIN * 64; i += 256) Ws[i] = W[i];
    if (t < 64) Bs[t] = B[t];
    int tx = t & 15, ty = t >> 4;
    int c = t & 63, eg = t >> 6;
    float ssum[4] = {0, 0, 0, 0}, ssq[4] = {0, 0, 0, 0};
    for (int tile = blockIdx.x; tile < Ee / 64; tile += gridDim.x) {
        int te = tile * 64;
        __syncthreads();
        for (int e = eg; e < 64; e += 4) {
            int sr = ei[te + e], ds = ei[Ee + te + e];
            in_t[c * ES + e]        = h[(size_t)ds * 64 + c];
            in_t[(64 + c) * ES + e] = h[(size_t)sr * 64 + c];
        }
        if (t < 64) {
            int e = t;
            int sr = ei[te + e], ds = ei[Ee + te + e];
            float dx = p[ds * 3 + 0] - p[sr * 3 + 0];
            float dy = p[ds * 3 + 1] - p[sr * 3 + 1];
            float dz = p[ds * 3 + 2] - p[sr * 3 + 2];
            in_t[128 * ES + e] = dx * dx + dy * dy + dz * dz;
            float4 a4 = *(const float4*)&ea[(size_t)(te + e) * 4];
            in_t[129 * ES + e] = a4.x;
            in_t[130 * ES + e] = a4.y;
            in_t[131 * ES + e] = a4.z;
            in_t[132 * ES + e] = a4.w;
        }
        __syncthreads();
        float acc[4][4];
        #pragma unroll
        for (int i = 0; i < 4; i++)
            #pragma unroll
            for (int j = 0; j < 4; j++) acc[i][j] = Bs[4 * ty + j];
        for (int k = 0; k < KIN; k++) {
            float av[4], wv[4];
            *(float4*)av = *(const float4*)&in_t[k * ES + 4 * tx];
            *(float4*)wv = *(const float4*)&Ws[k * 64 + 4 * ty];
            #pragma unroll
            for (int i = 0; i < 4; i++)
                #pragma unroll
                for (int j = 0; j < 4; j++)
                    acc[i][j] += av[i] * wv[j];
        }
        #pragma unroll
        for (int i = 0; i < 4; i++) {
            size_t e = (size_t)te + 4 * tx + i;
            ushort4 o;
            o.x = f2bf(acc[i][0]); o.y = f2bf(acc[i][1]);
            o.z = f2bf(acc[i][2]); o.w = f2bf(acc[i][3]);
            *(ushort4*)&ybuf[e * 64 + 4 * ty] = o;
            float r0 = bf2f(o.x), r1 = bf2f(o.y), r2 = bf2f(o.z), r3 = bf2f(o.w);
            ssum[0] += r0; ssum[1] += r1; ssum[2] += r2; ssum[3] += r3;
            ssq[0] += r0 * r0; ssq[1] += r1 * r1; ssq[2] += r2 * r2; ssq[3] += r3 * r3;
        }
    }
    #pragma unroll
    for (int j = 0; j < 4; j++) {
        float s = ssum[j], q = ssq[j];
        #pragma unroll
        for (int o2 = 1; o2 < 16; o2 <<= 1) { s += __shfl_xor(s, o2); q += __shfl_xor(q, o2); }
        if (tx == 0) {
            atomicAdd(&stats_out[4 * ty + j], s);
            atomicAdd(&stats_out[64 + 4 * ty + j], q);
        }
    }
}

// --------------------------- edge: bn+relu -> lin(64->64) [+m_aggr scatter] + stats
// R8-exact scalar-FMA kernel; ybuf bf16 in-place.

template<int AGGR>
__global__ __launch_bounds__(256) void k_edge_lin64(
    const float* __restrict__ stats_in, const float* __restrict__ gg,
    const float* __restrict__ be,
    const float* __restrict__ W, const float* __restrict__ B,
    const int* __restrict__ ei, float* __restrict__ magg,
    u16* __restrict__ ybuf, float* __restrict__ stats_out)
{
    __shared__ float Ws[64 * 64];
    __shared__ float As[64], Cs[64], Bs[64];
    __shared__ float in_t[64 * ES];
    int t = threadIdx.x;
    if (t < 64) {
        float mean = stats_in[t] * (1.f / Ee);
        float var  = stats_in[64 + t] * (1.f / Ee) - mean * mean;
        float a = gg[t] * rsqrtf(var + EPS);
        As[t] = a; Cs[t] = be[t] - mean * a; Bs[t] = B[t];
    }
    for (int i = t; i < 64 * 64; i += 256) Ws[i] = W[i];
    int tx = t & 15, ty = t >> 4;
    int c = t & 63, eg = t >> 6;
    float ssum[4] = {0, 0, 0, 0}, ssq[4] = {0, 0, 0, 0};
    for (int tile = blockIdx.x; tile < Ee / 64; tile += gridDim.x) {
        int te = tile * 64;
        __syncthreads();
        for (int e = eg; e < 64; e += 4) {
            float y = bf2f(ybuf[(size_t)(te + e) * 64 + c]);
            in_t[c * ES + e] = fmaxf(As[c] * y + Cs[c], 0.f);
        }
        __syncthreads();
        float acc[4][4];
        #pragma unroll
        for (int i = 0; i < 4; i++)
            #pragma unroll
            for (int j = 0; j < 4; j++) acc[i][j] = Bs[4 * ty + j];
        for (int k = 0; k < 64; k++) {
            float av[4], wv[4];
            *(float4*)av = *(const float4*)&in_t[k * ES + 4 * tx];
            *(float4*)wv = *(const float4*)&Ws[k * 64 + 4 * ty];
            #pragma unroll
            for (int i = 0; i < 4; i++)
                #pragma unroll
                for (int j = 0; j < 4; j++)
                    acc[i][j] += av[i] * wv[j];
        }
        if (AGGR) {
            for (int e = eg; e < 64; e += 4) {
                int ds = ei[Ee + te + e];
                atomicAdd(&magg[(size_t)ds * 64 + c], in_t[c * ES + e]);
            }
        }
        #pragma unroll
        for (int i = 0; i < 4; i++) {
            size_t e = (size_t)te + 4 * tx + i;
            ushort4 o;
            o.x = f2bf(acc[i][0]); o.y = f2bf(acc[i][1]);
            o.z = f2bf(acc[i][2]); o.w = f2bf(acc[i][3]);
            *(ushort4*)&ybuf[e * 64 + 4 * ty] = o;
            float r0 = bf2f(o.x), r1 = bf2f(o.y), r2 = bf2f(o.z), r3 = bf2f(o.w);
            ssum[0] += r0; ssum[1] += r1; ssum[2] += r2; ssum[3] += r3;
            ssq[0] += r0 * r0; ssq[1] += r1 * r1; ssq[2] += r2 * r2; ssq[3] += r3 * r3;
        }
    }
    #pragma unroll
    for (int j = 0; j < 4; j++) {
        float s = ssum[j], q = ssq[j];
        #pragma unroll
        for (int o2 = 1; o2 < 16; o2 <<= 1) { s += __shfl_xor(s, o2); q += __shfl_xor(q, o2); }
        if (tx == 0) {
            atomicAdd(&stats_out[4 * ty + j], s);
            atomicAdd(&stats_out[64 + 4 * ty + j], q);
        }
    }
}

// ------------------------------- edge: bn+relu -> pos_lin2 (64->1) -> scatter pos update

__global__ __launch_bounds__(256) void k_pos2(
    const float* __restrict__ stats_in, const float* __restrict__ gg, const float* __restrict__ be,
    const float* __restrict__ W2, const float* __restrict__ B2,
    const float* __restrict__ p, const int* __restrict__ ei,
    const u16* __restrict__ ybuf, float* __restrict__ pagg)
{
    __shared__ float As[64], Cs[64], Ws[64];
    int t = threadIdx.x;
    if (t < 64) {
        float mean = stats_in[t] * (1.f / Ee);
        float var  = stats_in[64 + t] * (1.f / Ee) - mean * mean;
        float a = gg[t] * rsqrtf(var + EPS);
        As[t] = a; Cs[t] = be[t] - mean * a; Ws[t] = W2[t];
    }
    __syncthreads();
    int e = blockIdx.x * 256 + t;
    if (e >= Ee) return;
    float acc = B2[0];
    const u16* row = &ybuf[(size_t)e * 64];
    #pragma unroll
    for (int u = 0; u < 16; u++) {
        ushort4 y4 = *(const ushort4*)&row[4 * u];
        acc += fmaxf(As[4 * u + 0] * bf2f(y4.x) + Cs[4 * u + 0], 0.f) * Ws[4 * u + 0]
             + fmaxf(As[4 * u + 1] * bf2f(y4.y) + Cs[4 * u + 1], 0.f) * Ws[4 * u + 1]
             + fmaxf(As[4 * u + 2] * bf2f(y4.z) + Cs[4 * u + 2], 0.f) * Ws[4 * u + 2]
             + fmaxf(As[4 * u + 3] * bf2f(y4.w) + Cs[4 * u + 3], 0.f) * Ws[4 * u + 3];
    }
    int sr = ei[e], ds = ei[Ee + e];
    float dx = p[ds * 3 + 0] - p[sr * 3 + 0];
    float dy = p[ds * 3 + 1] - p[sr * 3 + 1];
    float dz = p[ds * 3 + 2] - p[sr * 3 + 2];
    atomicAdd(&pagg[ds * 3 + 0], dx * acc);
    atomicAdd(&pagg[ds * 3 + 1], dy * acc);
    atomicAdd(&pagg[ds * 3 + 2], dz * acc);
}

// ------------------------------------------- node: [h | m_aggr] (128 -> 64) + stats

__global__ __launch_bounds__(256) void k_node_lin1(
    const float* __restrict__ h, const float* __restrict__ magg,
    const float* __restrict__ W, const float* __restrict__ B,
    float* __restrict__ yn, float* __restrict__ stats_out)
{
    __shared__ float Ws[128 * 64];
    __shared__ float Bs[64];
    __shared__ float in_t[128 * ES];
    int t = threadIdx.x;
    for (int i = t; i < 128 * 64; i += 256) Ws[i] = W[i];
    if (t < 64) Bs[t] = B[t];
    int tx = t & 15, ty = t >> 4, c = t & 63, eg = t >> 6;
    float ssum[4] = {0, 0, 0, 0}, ssq[4] = {0, 0, 0, 0};
    int nT = (Nn + 63) / 64;
    for (int tile = blockIdx.x; tile < nT; tile += gridDim.x) {
        int te = tile * 64;
        __syncthreads();
        for (int e = eg; e < 64; e += 4) {
            int n = te + e;
            bool v = n < Nn;
            in_t[c * ES + e]        = v ? h[(size_t)n * 64 + c]    : 0.f;
            in_t[(64 + c) * ES + e] = v ? magg[(size_t)n * 64 + c] : 0.f;
        }
        __syncthreads();
        float acc[4][4];
        #pragma unroll
        for (int i = 0; i < 4; i++)
            #pragma unroll
            for (int j = 0; j < 4; j++) acc[i][j] = Bs[4 * ty + j];
        for (int k = 0; k < 128; k++) {
            float av[4], wv[4];
            *(float4*)av = *(const float4*)&in_t[k * ES + 4 * tx];
            *(float4*)wv = *(const float4*)&Ws[k * 64 + 4 * ty];
            #pragma unroll
            for (int i = 0; i < 4; i++)
                #pragma unroll
                for (int j = 0; j < 4; j++)
                    acc[i][j] += av[i] * wv[j];
        }
        #pragma unroll
        for (int i = 0; i < 4; i++) {
            int n = te + 4 * tx + i;
            if (n < Nn) {
                float4 o; o.x = acc[i][0]; o.y = acc[i][1]; o.z = acc[i][2]; o.w = acc[i][3];
                *(float4*)&yn[(size_t)n * 64 + 4 * ty] = o;
                #pragma unroll
                for (int j = 0; j < 4; j++) { ssum[j] += acc[i][j]; ssq[j] += acc[i][j] * acc[i][j]; }
            }
        }
    }
    #pragma unroll
    for (int j = 0; j < 4; j++) {
        float s = ssum[j], q = ssq[j];
        #pragma unroll
        for (int o2 = 1; o2 < 16; o2 <<= 1) { s += __shfl_xor(s, o2); q += __shfl_xor(q, o2); }
        if (tx == 0) {
            atomicAdd(&stats_out[4 * ty + j], s);
            atomicAdd(&stats_out[64 + 4 * ty + j], q);
        }
    }
}

// ------------------------------------------- node: bn+relu -> lin(64->64) + stats (in-place)

__global__ __launch_bounds__(256) void k_node_lin64(
    const float* __restrict__ stats_in, const float* __restrict__ gg, const float* __restrict__ be,
    const float* __restrict__ W, const float* __restrict__ B,
    float* __restrict__ yn, float* __restrict__ stats_out)
{
    __shared__ float Ws[64 * 64];
    __shared__ float As[64], Cs[64], Bs[64];
    __shared__ float in_t[64 * ES];
    int t = threadIdx.x;
    if (t < 64) {
        float mean = stats_in[t] * (1.f / Nn);
        float var  = stats_in[64 + t] * (1.f / Nn) - mean * mean;
        float a = gg[t] * rsqrtf(var + EPS);
        As[t] = a; Cs[t] = be[t] - mean * a; Bs[t] = B[t];
    }
    for (int i = t; i < 64 * 64; i += 256) Ws[i] = W[i];
    int tx = t & 15, ty = t >> 4, c = t & 63, eg = t >> 6;
    float ssum[4] = {0, 0, 0, 0}, ssq[4] = {0, 0, 0, 0};
    int nT = (Nn + 63) / 64;
    for (int tile = blockIdx.x; tile < nT; tile += gridDim.x) {
        int te = tile * 64;
        __syncthreads();
        for (int e = eg; e < 64; e += 4) {
            int n = te + e;
            float y = (n < Nn) ? yn[(size_t)n * 64 + c] : 0.f;
            in_t[c * ES + e] = fmaxf(As[c] * y + Cs[c], 0.f);
        }
        __syncthreads();
        float acc[4][4];
        #pragma unroll
        for (int i = 0; i < 4; i++)
            #pragma unroll
            for (int j = 0; j < 4; j++) acc[i][j] = Bs[4 * ty + j];
        for (int k = 0; k < 64; k++) {
            float av[4], wv[4];
            *(float4*)av = *(const float4*)&in_t[k * ES + 4 * tx];
            *(float4*)wv = *(const float4*)&Ws[k * 64 + 4 * ty];
            #pragma unroll
            for (int i = 0; i < 4; i++)
                #pragma unroll
                for (int j = 0; j < 4; j++)
                    acc[i][j] += av[i] * wv[j];
        }
        #pragma unroll
        for (int i = 0; i < 4; i++) {
            int n = te + 4 * tx + i;
            if (n < Nn) {
                float4 o; o.x = acc[i][0]; o.y = acc[i][1]; o.z = acc[i][2]; o.w = acc[i][3];
                *(float4*)&yn[(size_t)n * 64 + 4 * ty] = o;
                #pragma unroll
                for (int j = 0; j < 4; j++) { ssum[j] += acc[i][j]; ssq[j] += acc[i][j] * acc[i][j]; }
            }
        }
    }
    #pragma unroll
    for (int j = 0; j < 4; j++) {
        float s = ssum[j], q = ssq[j];
        #pragma unroll
        for (int o2 = 1; o2 < 16; o2 <<= 1) { s += __shfl_xor(s, o2); q += __shfl_xor(q, o2); }
        if (tx == 0) {
            atomicAdd(&stats_out[4 * ty + j], s);
            atomicAdd(&stats_out[64 + 4 * ty + j], q);
        }
    }
}

// ------------------------------------------- node: residual h += relu(bn(yn)); p update

__global__ __launch_bounds__(256) void k_node_update(
    const float* __restrict__ stats_in, const float* __restrict__ gg, const float* __restrict__ be,
    const float* __restrict__ yn, float* __restrict__ h,
    const float* __restrict__ p_in, float* __restrict__ p_out,
    const float* __restrict__ pagg, const float* __restrict__ deg)
{
    int i = blockIdx.x * 256 + threadIdx.x;
    if (i < Nn * 64) {
        int c = i & 63;
        float mean = stats_in[c] * (1.f / Nn);
        float var  = stats_in[64 + c] * (1.f / Nn) - mean * mean;
        float a = gg[c] * rsqrtf(var + EPS);
        float cc = be[c] - mean * a;
        h[i] += fmaxf(a * yn[i] + cc, 0.f);
    }
    if (i < Nn * 3) {
        float dg = fmaxf(deg[i / 3], 1.f);
        p_out[i] = p_in[i] + pagg[i] / dg;
    }
}

// ------------------------------------------- pooling + prediction head

__global__ __launch_bounds__(256) void k_pool(const int* __restrict__ batch,
    const float* __restrict__ h, float* __restrict__ pool)
{
    int i = blockIdx.x * 256 + threadIdx.x;
    if (i < Nn * 64) {
        int n = i >> 6, c = i & 63;
        atomicAdd(&pool[(size_t)batch[n] * 64 + c], h[i]);
    }
}

__global__ void k_out(const float* __restrict__ pool, const float* __restrict__ cnt,
    const float* __restrict__ W, const float* __restrict__ B, float* __restrict__ out)
{
    int g = threadIdx.x;
    if (g < 64) {
        float acc = 0.f;
        for (int c = 0; c < 64; c++) acc += pool[g * 64 + c] * W[c];
        out[g] = acc / fmaxf(cnt[g], 1.f) + B[0];
    }
}

// ---------------------------------------------------------------- launch

extern "C" void kernel_launch(void* const* d_in, const int* in_sizes, int n_in,
                              void* d_out, int out_size, void* d_ws, size_t ws_size,
                              hipStream_t stream)
{
    const float* x        = (const float*)d_in[0];
    const float* pos      = (const float*)d_in[1];
    const float* ea       = (const float*)d_in[2];
    const int*   ei       = (const int*)  d_in[3];
    const int*   batch    = (const int*)  d_in[4];
    const float* lin_in_w = (const float*)d_in[5];
    const float* lin_in_b = (const float*)d_in[6];
    const float* lin_pr_w = (const float*)d_in[7];
    const float* lin_pr_b = (const float*)d_in[8];
    const float* msg_w1   = (const float*)d_in[9];
    const float* msg_b1   = (const float*)d_in[10];
    const float* msg_g1   = (const float*)d_in[11];
    const float* msg_be1  = (const float*)d_in[12];
    const float* msg_w2   = (const float*)d_in[13];
    const float* msg_b2   = (const float*)d_in[14];
    const float* msg_g2   = (const float*)d_in[15];
    const float* msg_be2  = (const float*)d_in[16];
    const float* pos_w1   = (const float*)d_in[17];
    const float* pos_b1   = (const float*)d_in[18];
    const float* pos_g    = (const float*)d_in[19];
    const float* pos_be   = (const float*)d_in[20];
    const float* pos_w2   = (const float*)d_in[21];
    const float* pos_b2   = (const float*)d_in[22];
    const float* upd_w1   = (const float*)d_in[23];
    const float* upd_b1   = (const float*)d_in[24];
    const float* upd_g1   = (const float*)d_in[25];
    const float* upd_be1  = (const float*)d_in[26];
    const float* upd_w2   = (const float*)d_in[27];
    const float* upd_b2   = (const float*)d_in[28];
    const float* upd_g2   = (const float*)d_in[29];
    const float* upd_be2  = (const float*)d_in[30];
    float* out = (float*)d_out;

    float* ws = (float*)d_ws;
    size_t o = 0;
    float* h    = ws + o; o += (size_t)Nn * 64;
    u16*   ybuf = (u16*)(ws + o); o += (size_t)Ee * 64;  // bf16, uses half the slot
    float* yn   = ws + o; o += (size_t)Nn * 64;
    float* magg = ws + o; o += (size_t)Nn * 64;   // magg + pagg contiguous (one memset)
    float* pagg = ws + o; o += (size_t)Nn * 3;
    float* pws  = ws + o; o += (size_t)Nn * 3;
    float* stats= ws + o; o += 1280;              // stats..deg contiguous (one memset)
    float* pool = ws + o; o += 64 * 64;
    float* cnt  = ws + o; o += 64;
    float* deg  = ws + o; o += Nn;
    if (ws_size < o * sizeof(float)) return;

    hipMemsetAsync(stats, 0, (size_t)(1280 + 64 * 64 + 64 + Nn) * sizeof(float), stream);
    k_lin_in<<<(Nn * 64 + 255) / 256, 256, 0, stream>>>(x, lin_in_w, lin_in_b, h);
    k_deg<<<(Ee + 255) / 256, 256, 0, stream>>>(ei, deg);
    k_cnt<<<(Nn + 255) / 256, 256, 0, stream>>>(batch, cnt);

    for (int l = 0; l < 2; l++) {
        hipMemsetAsync(magg, 0, ((size_t)Nn * 64 + (size_t)Nn * 3) * sizeof(float), stream);
        const float* pc = (l == 0) ? pos : pws;
        float* st = stats + (size_t)l * 5 * 128;
        k_edge_lin1<<<512, 256, 0, stream>>>(h, pc, ea, ei,
            msg_w1 + (size_t)l * KIN * 64, msg_b1 + l * 64, ybuf, st + 0 * 128);
        k_edge_lin64<0><<<1024, 256, 0, stream>>>(st + 0 * 128, msg_g1 + l * 64, msg_be1 + l * 64,
            msg_w2 + (size_t)l * 64 * 64, msg_b2 + l * 64, ei, nullptr, ybuf, st + 1 * 128);
        k_edge_lin64<1><<<1024, 256, 0, stream>>>(st + 1 * 128, msg_g2 + l * 64, msg_be2 + l * 64,
            pos_w1 + (size_t)l * 64 * 64, pos_b1 + l * 64, ei, magg, ybuf, st + 2 * 128);
        k_pos2<<<(Ee + 255) / 256, 256, 0, stream>>>(st + 2 * 128, pos_g + l * 64, pos_be + l * 64,
            pos_w2 + l * 64, pos_b2 + l, pc, ei, ybuf, pagg);
        k_node_lin1<<<782, 256, 0, stream>>>(h, magg,
            upd_w1 + (size_t)l * 128 * 64, upd_b1 + l * 64, yn, st + 3 * 128);
        k_node_lin64<<<782, 256, 0, stream>>>(st + 3 * 128, upd_g1 + l * 64, upd_be1 + l * 64,
            upd_w2 + (size_t)l * 64 * 64, upd_b2 + l * 64, yn, st + 4 * 128);
        k_node_update<<<(Nn * 64 + 255) / 256, 256, 0, stream>>>(st + 4 * 128,
            upd_g2 + l * 64, upd_be2 + l * 64, yn, h, pc, pws, pagg, deg);
    }
    k_pool<<<(Nn * 64 + 255) / 256, 256, 0, stream>>>(batch, h, pool);
    k_out<<<1, 64, 0, stream>>>(pool, cnt, lin_pr_w, lin_pr_b, out);
}